// Round 11
// baseline (113.121 us; speedup 1.0000x reference)
//
#include <hip/hip_runtime.h>
#include <stdint.h>

// Problem constants (fixed by reference setup_inputs)
#define CIN   256
#define COUT  256
#define Hdim  56
#define Wdim  56
#define HW    3136        // 56*56
#define BATCH 32
#define NPIX  100352      // 32*3136
#define KREP  589824      // 256*256*9, stride between weight replicas
#define TAPS  9
#define WORDS 8           // 8 x uint32 = 256 channel bits

// ws layout (bytes). First 3,286,016 B = R7-proven footprint (fallback path).
// W8 (expanded int8 weights, stream-contiguous layout) appended past it.
#define OFF_WBT   0         // 9*2*256*8 ushorts = 73728
#define OFF_SA    73728     // 256*4 = 1024
#define OFF_XBITS 74752     // 100352*8*4 = 3211264
#define OFF_W8    3286016   // 8 cg * 9 t * 8 c * 1024 B = 589824
#define WS_NEED   (OFF_W8 + 589824)

#define CGBYTES   73728     // W8 bytes per 32-co group (9*8*1024)

typedef int int4v  __attribute__((ext_vector_type(4)));
typedef int int16v __attribute__((ext_vector_type(16)));

// 4 sign bits -> 4 int8 lanes of {-1,+1}. Byte-borrow-proof:
// (0x81 - 2b) ^ 0x80 = {0x01, 0xFF} per byte, no cross-byte borrow.
__device__ __forceinline__ uint32_t nib2pm1(uint32_t n) {
    const uint32_t mask = (n * 0x204081u) & 0x01010101u;
    return (0x81818181u - (mask << 1)) ^ 0x80808080u;
}

__device__ __forceinline__ int4v expand_pm1(uint32_t us) {
    int4v r;
    r.x = (int)nib2pm1(us & 15u);
    r.y = (int)nib2pm1((us >> 4) & 15u);
    r.z = (int)nib2pm1((us >> 8) & 15u);
    r.w = (int)nib2pm1((us >> 12) & 15u);
    return r;
}

__device__ __forceinline__ uint32_t ext16(const uint4 v, int c) {
    uint32_t comp = (c < 4) ? ((c < 2) ? v.x : v.y) : ((c < 6) ? v.z : v.w);
    return (c & 1) ? (comp >> 16) : (comp & 0xFFFFu);
}

// ---------------------------------------------------------------------------
// P1: real_w = sum_k RV[k]*W[k]; sa[co] = mean|real_w| * alpha[co];
//     wbT bit-pack (fallback) and W8 expanded int8 B-fragments in the
//     stream-contiguous layout: byte = (co>>5)*73728 + (t*8+c)*1024
//     + g*512 + (co&31)*16  (g = ci 16-half). Same bytes as the R8-verified
//     W8, new addresses only.
// ---------------------------------------------------------------------------
__global__ __launch_bounds__(256) void prep_w_kernel(
    const float* __restrict__ wts, const float* __restrict__ RV,
    const float* __restrict__ alpha, unsigned short* __restrict__ wbT,
    float* __restrict__ sa, uint4* __restrict__ w8, int do_w8)
{
    __shared__ uint32_t bits[TAPS * WORDS];   // bits[tap*8 + (ci>>5)]
    __shared__ float    red[256];

    const int co = blockIdx.x;
    const int t  = threadIdx.x;

    if (t < TAPS * WORDS) bits[t] = 0u;
    __syncthreads();

    const float r0 = RV[0], r1 = RV[1], r2 = RV[2], r3 = RV[3];
    const float* base = wts + (size_t)co * 2304;

    float acc = 0.f;
#pragma unroll
    for (int j = 0; j < 9; ++j) {
        const int e = j * 256 + t;              // e = ci*9 + tap
        const float w0 = base[e];
        const float w1 = base[e + KREP];
        const float w2 = base[e + 2 * KREP];
        const float w3 = base[e + 3 * KREP];
        const float rw = r0 * w0 + r1 * w1 + r2 * w2 + r3 * w3;
        acc += fabsf(rw);
        const int ci  = e / 9;
        const int tap = e - ci * 9;
        if (rw < 0.f)
            atomicOr(&bits[tap * WORDS + (ci >> 5)], 1u << (ci & 31));
    }
    red[t] = acc;
    __syncthreads();

    for (int s = 128; s > 0; s >>= 1) {
        if (t < s) red[t] += red[t + s];
        __syncthreads();
    }

    if (t == 0) sa[co] = (red[0] * (1.0f / 2304.0f)) * alpha[co];

    if (t < 144) {                       // wbT: (tap, g, c) — R7-verified
        const int tap = t >> 4;
        const int r   = t & 15;
        const int g   = r >> 3;
        const int c   = r & 7;
        const uint32_t v = (bits[tap * 8 + c] >> (g * 16)) & 0xFFFFu;
        wbT[(((tap * 2 + g) * 256 + co) << 3) + c] = (unsigned short)v;
    }
    if (do_w8 && t < 144) {              // W8 stream layout: (tap, q=2c+g)
        const int tap = t >> 4;
        const int q   = t & 15;
        const int c   = q >> 1;
        const int g   = q & 1;
        const uint32_t v = (bits[tap * 8 + c] >> (g * 16)) & 0xFFFFu;
        uint4 e;
        e.x = nib2pm1(v & 15u);
        e.y = nib2pm1((v >> 4) & 15u);
        e.z = nib2pm1((v >> 8) & 15u);
        e.w = nib2pm1((v >> 12) & 15u);
        // uint4 index: cg*4608 + (tap*8+c)*64 + g*32 + (co&31)
        w8[(co >> 5) * 4608 + (tap * 8 + c) * 64 + g * 32 + (co & 31)] = e;
    }
}

// ---------------------------------------------------------------------------
// P2: binarize+pack x (unpadded [B][56][56][8]) — unchanged, verified R1.
// ---------------------------------------------------------------------------
__global__ __launch_bounds__(256) void pack_x_kernel(
    const float* __restrict__ x, uint32_t* __restrict__ xbits)
{
    const int p  = blockIdx.x * 256 + threadIdx.x;   // pixel id < NPIX
    const int b  = p / HW;
    const int hw = p - b * HW;
    const float* xp = x + (size_t)b * CIN * HW + hw;

    uint32_t wv[WORDS];
#pragma unroll
    for (int j = 0; j < WORDS; ++j) {
        uint32_t m = 0;
#pragma unroll
        for (int bit = 0; bit < 32; ++bit) {
            const float v = xp[(size_t)(j * 32 + bit) * HW];
            m |= (__float_as_uint(v) >> 31) << bit;
        }
        wv[j] = m;
    }
    uint4* dst = (uint4*)(xbits + (size_t)p * WORDS);
    dst[0] = make_uint4(wv[0], wv[1], wv[2], wv[3]);
    dst[1] = make_uint4(wv[4], wv[5], wv[6], wv[7]);
}

// ---------------------------------------------------------------------------
// C (primary): implicit-GEMM XNOR conv, row-aligned 112-px M-tile.
// B-loads: one fully-coalesced 1 KB transaction per (stream, k-step) at
// uniform_base + lane*16 + k*1024 (imm-offset addressing, no per-load
// 64-bit VALU chains). s_setprio(1) around the MFMA quad (T5: free-running
// waves, no K-loop barriers). Geometry/staging/epilogue = R9-verified.
// ---------------------------------------------------------------------------
__global__ __launch_bounds__(512, 4) void conv_mfma_w8_kernel(
    const uint32_t* __restrict__ xbits, const uint8_t* __restrict__ w8,
    const float* __restrict__ sa_g, float* __restrict__ out)
{
    __shared__ __align__(16) int xt[232 * 64];  // 4 rows x 58 cols x 256B

    const int tid  = threadIdx.x;
    const int lane = tid & 63;
    const int half = lane >> 5;
    const int l31  = lane & 31;
    const int wid  = tid >> 6;
    const int mg   = wid >> 2;       // M-group 0..1 (px 0-63 / 64-111(+pad))
    const int ng   = wid & 3;        // N-group 0..3

    const int blk = blockIdx.x;
    const int b   = blk / 28;
    const int T   = blk - b * 28;
    const int p0  = T * 112;
    const int h0  = 2 * T;           // first output row (aligned)

    // ---- stage + expand x tile (rows h0-1 .. h0+2, cols -1..56, pad = 0)
    {
        const uint32_t* xb = xbits + (size_t)b * (HW * WORDS);
        for (int u = tid; u < 232 * 32; u += 512) {   // b64 units
            const int cell = u >> 5, p = u & 31;
            const int row = cell / 58;                // 0..3
            const int col = cell - row * 58;          // 0..57
            const int hh = h0 - 1 + row, ww = col - 1;
            const bool ok = (hh >= 0) && (hh < Hdim) && (ww >= 0) && (ww < Wdim);
            uint32_t byteval = 0;
            if (ok)
                byteval = (xb[((hh * 56 + ww) << 3) + (p >> 2)] >> ((p & 3) * 8)) & 0xFFu;
            uint32_t d0 = nib2pm1(byteval & 15u);
            uint32_t d1 = nib2pm1(byteval >> 4);
            if (!ok) { d0 = 0u; d1 = 0u; }            // pad contributes 0
            const int f   = (col + 2 * row) & 15;
            const int idx = cell * 64 + (((p >> 1) ^ f) << 2) + ((p & 1) << 1);
            *reinterpret_cast<uint2*>(&xt[idx]) = make_uint2(d0, d1);
        }
    }
    __syncthreads();

    // ---- per-lane geometry (R9-verified)
    const int m0  = mg * 64 + l31;            // 0..95   (always valid < 112)
    const int m1  = m0 + 32;                  // 32..127 (invalid >= 112)
    const int m1c = (m1 < 112) ? m1 : 111;    // clamp for addressing only
    const int rb0 = m0 / 56,  w_0 = m0 - rb0 * 56;
    const int rb1 = m1c / 56, w_1 = m1c - rb1 * 56;

    const int co0 = ng * 64 + l31;
    const int co1 = co0 + 32;
    const float s0 = sa_g[co0], s1 = sa_g[co1];

    // B stream base: lane*16 folds in (half, co31); k*1024 walks the stream.
    const uint8_t* w8s = w8 + (size_t)(ng * 2) * CGBYTES + (lane << 4);

    int16v a00 = {0,0,0,0,0,0,0,0,0,0,0,0,0,0,0,0};
    int16v a01 = {0,0,0,0,0,0,0,0,0,0,0,0,0,0,0,0};
    int16v a10 = {0,0,0,0,0,0,0,0,0,0,0,0,0,0,0,0};
    int16v a11 = {0,0,0,0,0,0,0,0,0,0,0,0,0,0,0,0};

#pragma unroll 1
    for (int t = 0; t < 9; ++t) {
        const int kh = (t * 11) >> 5;                  // t/3 for t<9
        const int kw = t - kh * 3;
        const int cb0 = ((rb0 + kh) * 58 + w_0 + kw) * 64;
        const int f0  = (w_0 + kw + 2 * (rb0 + kh)) & 15;
        const int cb1 = ((rb1 + kh) * 58 + w_1 + kw) * 64;
        const int f1  = (w_1 + kw + 2 * (rb1 + kh)) & 15;
        const uint8_t* q0 = w8s + (size_t)t * 8192;          // co0 stream
        const uint8_t* q1 = q0 + CGBYTES;                    // co1 stream

#pragma unroll
        for (int c = 0; c < 8; ++c) {
            const int4v bv0 = *(const int4v*)(q0 + c * 1024);
            const int4v bv1 = *(const int4v*)(q1 + c * 1024);
            const int g0 = ((((c << 1) | half) ^ f0) << 2);
            const int g1 = ((((c << 1) | half) ^ f1) << 2);
            const int4v av0 = *(const int4v*)&xt[cb0 + g0];
            const int4v av1 = *(const int4v*)&xt[cb1 + g1];
            __builtin_amdgcn_s_setprio(1);
            a00 = __builtin_amdgcn_mfma_i32_32x32x32_i8(av0, bv0, a00, 0, 0, 0);
            a01 = __builtin_amdgcn_mfma_i32_32x32x32_i8(av0, bv1, a01, 0, 0, 0);
            a10 = __builtin_amdgcn_mfma_i32_32x32x32_i8(av1, bv0, a10, 0, 0, 0);
            a11 = __builtin_amdgcn_mfma_i32_32x32x32_i8(av1, bv1, a11, 0, 0, 0);
            __builtin_amdgcn_s_setprio(0);
        }
    }

    // ---- epilogue: 4 rounds of 32 px through LDS transpose (obuf <= xt).
    // Round r: mg (r>>1), frag (r&1); round 3 rows >=16 are clamp-garbage.
    __syncthreads();                      // all xt reads done
    float* obuf = (float*)xt;             // [32][257] floats = 32896 B
    float* ob = out + (size_t)b * (COUT * HW);

#pragma unroll 1
    for (int r = 0; r < 4; ++r) {
        if (mg == (r >> 1)) {
            const int rfr = r & 1;
#pragma unroll
            for (int reg = 0; reg < 16; ++reg) {
                const int row = (reg & 3) + ((reg >> 2) << 3) + (half << 2);
                if (r == 3 && row >= 16) continue;    // invalid px 112..127
                if (rfr == 0) {
                    obuf[row * 257 + co0] = s0 * (float)a00[reg];
                    obuf[row * 257 + co1] = s1 * (float)a01[reg];
                } else {
                    obuf[row * 257 + co0] = s0 * (float)a10[reg];
                    obuf[row * 257 + co1] = s1 * (float)a11[reg];
                }
            }
        }
        __syncthreads();
        const int k  = tid & 31;          // px within round
        const int cb = tid >> 5;          // 0..15
        const int pxb = p0 + r * 32;
        if (r < 3 || k < 16) {
#pragma unroll
            for (int j = 0; j < 16; ++j) {
                const int co = cb + 16 * j;
                ob[(size_t)co * HW + pxb + k] = obuf[k * 257 + co];
            }
        }
        __syncthreads();
    }
}

// ---------------------------------------------------------------------------
// C (fallback, ws too small for W8): exact R7 kernel — verified pass @140us.
// ---------------------------------------------------------------------------
__global__ __launch_bounds__(512, 2) void conv_mfma_kernel(
    const uint32_t* __restrict__ xbits, const unsigned short* __restrict__ wbT,
    const float* __restrict__ sa_g, float* __restrict__ out)
{
    __shared__ __align__(16) int xt[348 * 64];

    const int tid  = threadIdx.x;
    const int lane = tid & 63;
    const int half = lane >> 5;
    const int l31  = lane & 31;
    const int wid  = tid >> 6;
    const int mg   = wid >> 2;
    const int ng   = wid & 3;

    const int blk = blockIdx.x;
    const int b   = blk / 25;
    const int T   = blk - b * 25;
    const int p0  = T * 128;
    const bool full = (T < 24);
    const int mgE = full ? mg : 0;
    const int h0  = p0 / 56;

    {
        const uint32_t* xb = xbits + (size_t)b * (HW * WORDS);
        for (int u = tid; u < 348 * 32; u += 512) {
            const int cell = u >> 5, p = u & 31;
            const int row = cell / 58;
            const int col = cell - row * 58;
            const int hh = h0 - 1 + row, ww = col - 1;
            const bool ok = (hh >= 0) && (hh < Hdim) && (ww >= 0) && (ww < Wdim);
            uint32_t byteval = 0;
            if (ok)
                byteval = (xb[((hh * 56 + ww) << 3) + (p >> 2)] >> ((p & 3) * 8)) & 0xFFu;
            uint32_t d0 = nib2pm1(byteval & 15u);
            uint32_t d1 = nib2pm1(byteval >> 4);
            if (!ok) { d0 = 0u; d1 = 0u; }
            const int f   = (col + 2 * row) & 15;
            const int idx = cell * 64 + (((p >> 1) ^ f) << 2) + ((p & 1) << 1);
            *reinterpret_cast<uint2*>(&xt[idx]) = make_uint2(d0, d1);
        }
    }
    __syncthreads();

    const int px0 = p0 + mgE * 64 + l31;
    const int px1 = px0 + 32;
    const int h_0 = px0 / 56, w_0 = px0 - h_0 * 56;
    const int h_1 = px1 / 56, w_1 = px1 - h_1 * 56;
    const int rb0 = h_0 - h0, rb1 = h_1 - h0;

    const int co0 = ng * 64 + l31;
    const int co1 = co0 + 32;
    const float s0 = sa_g[co0], s1 = sa_g[co1];

    const unsigned short* wp0 = wbT + (((half << 8) + co0) << 3);
    const unsigned short* wp1 = wbT + (((half << 8) + co1) << 3);

    int16v a00 = {0,0,0,0,0,0,0,0,0,0,0,0,0,0,0,0};
    int16v a01 = {0,0,0,0,0,0,0,0,0,0,0,0,0,0,0,0};
    int16v a10 = {0,0,0,0,0,0,0,0,0,0,0,0,0,0,0,0};
    int16v a11 = {0,0,0,0,0,0,0,0,0,0,0,0,0,0,0,0};

    uint4 wb0 = *(const uint4*)wp0;
    uint4 wb1 = *(const uint4*)wp1;

#pragma unroll 1
    for (int t = 0; t < 9; ++t) {
        const int tn = (t < 8) ? (t + 1) : 8;
        const uint4 wb0n = *(const uint4*)(wp0 + tn * 4096);
        const uint4 wb1n = *(const uint4*)(wp1 + tn * 4096);

        const int kh = (t * 11) >> 5;
        const int kw = t - kh * 3;
        const int cb0 = ((rb0 + kh) * 58 + w_0 + kw) * 64;
        const int f0  = (w_0 + kw + 2 * (rb0 + kh)) & 15;
        const int cb1 = ((rb1 + kh) * 58 + w_1 + kw) * 64;
        const int f1  = (w_1 + kw + 2 * (rb1 + kh)) & 15;

#pragma unroll
        for (int c = 0; c < 8; ++c) {
            const int g0 = ((((c << 1) | half) ^ f0) << 2);
            const int g1 = ((((c << 1) | half) ^ f1) << 2);
            const int4v av0 = *(const int4v*)&xt[cb0 + g0];
            const int4v av1 = *(const int4v*)&xt[cb1 + g1];
            const int4v bv0 = expand_pm1(ext16(wb0, c));
            const int4v bv1 = expand_pm1(ext16(wb1, c));
            a00 = __builtin_amdgcn_mfma_i32_32x32x32_i8(av0, bv0, a00, 0, 0, 0);
            a01 = __builtin_amdgcn_mfma_i32_32x32x32_i8(av0, bv1, a01, 0, 0, 0);
            a10 = __builtin_amdgcn_mfma_i32_32x32x32_i8(av1, bv0, a10, 0, 0, 0);
            a11 = __builtin_amdgcn_mfma_i32_32x32x32_i8(av1, bv1, a11, 0, 0, 0);
        }
        wb0 = wb0n; wb1 = wb1n;
    }

    if (full || mg == 0) {
        float* ob = out + (size_t)b * (COUT * HW);
        const int pxb = p0 + mgE * 64;
#pragma unroll
        for (int reg = 0; reg < 16; ++reg) {
            const int row = (reg & 3) + ((reg >> 2) << 3) + (half << 2);
            ob[(size_t)co0 * HW + pxb + row]      = s0 * (float)a00[reg];
            ob[(size_t)co1 * HW + pxb + row]      = s1 * (float)a01[reg];
            ob[(size_t)co0 * HW + pxb + 32 + row] = s0 * (float)a10[reg];
            ob[(size_t)co1 * HW + pxb + 32 + row] = s1 * (float)a11[reg];
        }
    }
}

extern "C" void kernel_launch(void* const* d_in, const int* in_sizes, int n_in,
                              void* d_out, int out_size, void* d_ws, size_t ws_size,
                              hipStream_t stream) {
    const float* x     = (const float*)d_in[0];   // [32,256,56,56]
    const float* wts   = (const float*)d_in[1];   // [4,256,256,3,3]
    const float* RV    = (const float*)d_in[2];   // [5]
    const float* alpha = (const float*)d_in[3];   // [256,1,1]
    float* out = (float*)d_out;                   // [32,256,56,56]

    uint8_t* ws = (uint8_t*)d_ws;
    unsigned short* wbT = (unsigned short*)(ws + OFF_WBT);
    float*    sa    = (float*)   (ws + OFF_SA);
    uint32_t* xbits = (uint32_t*)(ws + OFF_XBITS);
    uint4*    w8    = (uint4*)   (ws + OFF_W8);

    const int has_w8 = (ws_size >= (size_t)WS_NEED) ? 1 : 0;

    prep_w_kernel<<<COUT, 256, 0, stream>>>(wts, RV, alpha, wbT, sa, w8, has_w8);
    pack_x_kernel<<<NPIX / 256, 256, 0, stream>>>(x, xbits);
    if (has_w8)
        conv_mfma_w8_kernel<<<BATCH * 28, 512, 0, stream>>>(
            xbits, (const uint8_t*)w8, sa, out);
    else
        conv_mfma_kernel<<<BATCH * 25, 512, 0, stream>>>(xbits, wbT, sa, out);
}

// Round 13
// 106.785 us; speedup vs baseline: 1.0593x; 1.0593x over previous
//
#include <hip/hip_runtime.h>
#include <stdint.h>

// Problem constants (fixed by reference setup_inputs)
#define CIN   256
#define COUT  256
#define Hdim  56
#define Wdim  56
#define HW    3136        // 56*56
#define BATCH 32
#define NPIX  100352      // 32*3136
#define KREP  589824      // 256*256*9, stride between weight replicas
#define TAPS  9
#define WORDS 8           // 8 x uint32 = 256 channel bits

// ws layout (bytes). First 3,286,016 B = R7-proven footprint (fallback path).
// W8 (expanded int8 weights, stream-contiguous layout) appended past it.
#define OFF_WBT   0         // 9*2*256*8 ushorts = 73728
#define OFF_SA    73728     // 256*4 = 1024
#define OFF_XBITS 74752     // 100352*8*4 = 3211264
#define OFF_W8    3286016   // 8 cg * 9 t * 8 c * 1024 B = 589824
#define WS_NEED   (OFF_W8 + 589824)

#define CGBYTES   73728     // W8 bytes per 32-co group (9*8*1024)

typedef int int4v  __attribute__((ext_vector_type(4)));
typedef int int16v __attribute__((ext_vector_type(16)));

// 4 sign bits -> 4 int8 lanes of {-1,+1}. Byte-borrow-proof:
// (0x81 - 2b) ^ 0x80 = {0x01, 0xFF} per byte, no cross-byte borrow.
__device__ __forceinline__ uint32_t nib2pm1(uint32_t n) {
    const uint32_t mask = (n * 0x204081u) & 0x01010101u;
    return (0x81818181u - (mask << 1)) ^ 0x80808080u;
}

__device__ __forceinline__ int4v expand_pm1(uint32_t us) {
    int4v r;
    r.x = (int)nib2pm1(us & 15u);
    r.y = (int)nib2pm1((us >> 4) & 15u);
    r.z = (int)nib2pm1((us >> 8) & 15u);
    r.w = (int)nib2pm1((us >> 12) & 15u);
    return r;
}

__device__ __forceinline__ uint32_t ext16(const uint4 v, int c) {
    uint32_t comp = (c < 4) ? ((c < 2) ? v.x : v.y) : ((c < 6) ? v.z : v.w);
    return (c & 1) ? (comp >> 16) : (comp & 0xFFFFu);
}

// ---------------------------------------------------------------------------
// P1: real_w = sum_k RV[k]*W[k]; sa[co] = mean|real_w| * alpha[co];
//     wbT bit-pack (fallback) and W8 expanded int8 B-fragments in the
//     stream-contiguous layout: byte = (co>>5)*73728 + (t*8+c)*1024
//     + g*512 + (co&31)*16. Verified R11 (same bytes as R8's W8).
// ---------------------------------------------------------------------------
__global__ __launch_bounds__(256) void prep_w_kernel(
    const float* __restrict__ wts, const float* __restrict__ RV,
    const float* __restrict__ alpha, unsigned short* __restrict__ wbT,
    float* __restrict__ sa, uint4* __restrict__ w8, int do_w8)
{
    __shared__ uint32_t bits[TAPS * WORDS];   // bits[tap*8 + (ci>>5)]
    __shared__ float    red[256];

    const int co = blockIdx.x;
    const int t  = threadIdx.x;

    if (t < TAPS * WORDS) bits[t] = 0u;
    __syncthreads();

    const float r0 = RV[0], r1 = RV[1], r2 = RV[2], r3 = RV[3];
    const float* base = wts + (size_t)co * 2304;

    float acc = 0.f;
#pragma unroll
    for (int j = 0; j < 9; ++j) {
        const int e = j * 256 + t;              // e = ci*9 + tap
        const float w0 = base[e];
        const float w1 = base[e + KREP];
        const float w2 = base[e + 2 * KREP];
        const float w3 = base[e + 3 * KREP];
        const float rw = r0 * w0 + r1 * w1 + r2 * w2 + r3 * w3;
        acc += fabsf(rw);
        const int ci  = e / 9;
        const int tap = e - ci * 9;
        if (rw < 0.f)
            atomicOr(&bits[tap * WORDS + (ci >> 5)], 1u << (ci & 31));
    }
    red[t] = acc;
    __syncthreads();

    for (int s = 128; s > 0; s >>= 1) {
        if (t < s) red[t] += red[t + s];
        __syncthreads();
    }

    if (t == 0) sa[co] = (red[0] * (1.0f / 2304.0f)) * alpha[co];

    if (t < 144) {                       // wbT: (tap, g, c) — R7-verified
        const int tap = t >> 4;
        const int r   = t & 15;
        const int g   = r >> 3;
        const int c   = r & 7;
        const uint32_t v = (bits[tap * 8 + c] >> (g * 16)) & 0xFFFFu;
        wbT[(((tap * 2 + g) * 256 + co) << 3) + c] = (unsigned short)v;
    }
    if (do_w8 && t < 144) {              // W8 stream layout: (tap, q=2c+g)
        const int tap = t >> 4;
        const int q   = t & 15;
        const int c   = q >> 1;
        const int g   = q & 1;
        const uint32_t v = (bits[tap * 8 + c] >> (g * 16)) & 0xFFFFu;
        uint4 e;
        e.x = nib2pm1(v & 15u);
        e.y = nib2pm1((v >> 4) & 15u);
        e.z = nib2pm1((v >> 8) & 15u);
        e.w = nib2pm1((v >> 12) & 15u);
        // uint4 index: cg*4608 + (tap*8+c)*64 + g*32 + (co&31)
        w8[(co >> 5) * 4608 + (tap * 8 + c) * 64 + g * 32 + (co & 31)] = e;
    }
}

// ---------------------------------------------------------------------------
// P2: binarize+pack x (unpadded [B][56][56][8]) — unchanged, verified R1.
// ---------------------------------------------------------------------------
__global__ __launch_bounds__(256) void pack_x_kernel(
    const float* __restrict__ x, uint32_t* __restrict__ xbits)
{
    const int p  = blockIdx.x * 256 + threadIdx.x;   // pixel id < NPIX
    const int b  = p / HW;
    const int hw = p - b * HW;
    const float* xp = x + (size_t)b * CIN * HW + hw;

    uint32_t wv[WORDS];
#pragma unroll
    for (int j = 0; j < WORDS; ++j) {
        uint32_t m = 0;
#pragma unroll
        for (int bit = 0; bit < 32; ++bit) {
            const float v = xp[(size_t)(j * 32 + bit) * HW];
            m |= (__float_as_uint(v) >> 31) << bit;
        }
        wv[j] = m;
    }
    uint4* dst = (uint4*)(xbits + (size_t)p * WORDS);
    dst[0] = make_uint4(wv[0], wv[1], wv[2], wv[3]);
    dst[1] = make_uint4(wv[4], wv[5], wv[6], wv[7]);
}

// ---------------------------------------------------------------------------
// C (primary): implicit-GEMM XNOR conv, row-aligned 112-px M-tile, with an
// ASM-FORCED rotating 4-deep B pipeline (T4 counted vmcnt). R12 NaN fix:
// (a) post-loop s_waitcnt vmcnt(0) tied to all 8 B slots — keeps them live
//     so regalloc can't hand their registers to the epilogue while the
//     final (unconsumed) prefetch loads are still in flight;
// (b) "=&v" early-clobber on ISSUE so a load's dst can never be allocated
//     over its still-needed base-address pair.
// No setprio (R11 regression). Geometry/staging/epilogue = R9-verified.
// ---------------------------------------------------------------------------
__global__ __launch_bounds__(512, 4) void conv_mfma_w8_kernel(
    const uint32_t* __restrict__ xbits, const uint8_t* __restrict__ w8,
    const float* __restrict__ sa_g, float* __restrict__ out)
{
    __shared__ __align__(16) int xt[232 * 64];  // 4 rows x 58 cols x 256B

    const int tid  = threadIdx.x;
    const int lane = tid & 63;
    const int half = lane >> 5;
    const int l31  = lane & 31;
    const int wid  = tid >> 6;
    const int mg   = wid >> 2;       // M-group 0..1 (px 0-63 / 64-111(+pad))
    const int ng   = wid & 3;        // N-group 0..3

    const int blk = blockIdx.x;
    const int b   = blk / 28;
    const int T   = blk - b * 28;
    const int p0  = T * 112;
    const int h0  = 2 * T;           // first output row (aligned)

    // ---- stage + expand x tile (rows h0-1 .. h0+2, cols -1..56, pad = 0)
    {
        const uint32_t* xb = xbits + (size_t)b * (HW * WORDS);
        for (int u = tid; u < 232 * 32; u += 512) {   // b64 units
            const int cell = u >> 5, p = u & 31;
            const int row = cell / 58;                // 0..3
            const int col = cell - row * 58;          // 0..57
            const int hh = h0 - 1 + row, ww = col - 1;
            const bool ok = (hh >= 0) && (hh < Hdim) && (ww >= 0) && (ww < Wdim);
            uint32_t byteval = 0;
            if (ok)
                byteval = (xb[((hh * 56 + ww) << 3) + (p >> 2)] >> ((p & 3) * 8)) & 0xFFu;
            uint32_t d0 = nib2pm1(byteval & 15u);
            uint32_t d1 = nib2pm1(byteval >> 4);
            if (!ok) { d0 = 0u; d1 = 0u; }            // pad contributes 0
            const int f   = (col + 2 * row) & 15;
            const int idx = cell * 64 + (((p >> 1) ^ f) << 2) + ((p & 1) << 1);
            *reinterpret_cast<uint2*>(&xt[idx]) = make_uint2(d0, d1);
        }
    }
    __syncthreads();

    // ---- per-lane geometry (R9-verified)
    const int m0  = mg * 64 + l31;            // 0..95   (always valid < 112)
    const int m1  = m0 + 32;                  // 32..127 (invalid >= 112)
    const int m1c = (m1 < 112) ? m1 : 111;    // clamp for addressing only
    const int rb0 = m0 / 56,  w_0 = m0 - rb0 * 56;
    const int rb1 = m1c / 56, w_1 = m1c - rb1 * 56;

    const int co0 = ng * 64 + l31;
    const int co1 = co0 + 32;
    const float s0 = sa_g[co0], s1 = sa_g[co1];

    // B stream bases: lane*16 folds in (half, co31); k*1024 walks the stream.
    const uint8_t* w8sA = w8 + (size_t)(ng * 2) * CGBYTES + (lane << 4);
    const uint8_t* w8sB = w8sA + CGBYTES;

    int16v a00 = {0,0,0,0,0,0,0,0,0,0,0,0,0,0,0,0};
    int16v a01 = {0,0,0,0,0,0,0,0,0,0,0,0,0,0,0,0};
    int16v a10 = {0,0,0,0,0,0,0,0,0,0,0,0,0,0,0,0};
    int16v a11 = {0,0,0,0,0,0,0,0,0,0,0,0,0,0,0,0};

    int4v B0[4], B1[4];

#define ISSUE(DST, BASE, OFFLIT)                                             \
    asm volatile("global_load_dwordx4 %0, %1, off offset:" OFFLIT           \
                 : "=&v"(DST) : "v"(BASE))

    // prologue: issue k = 0..3 (8 loads in flight)
    ISSUE(B0[0], w8sA, "0");    ISSUE(B1[0], w8sB, "0");
    ISSUE(B0[1], w8sA, "1024"); ISSUE(B1[1], w8sB, "1024");
    ISSUE(B0[2], w8sA, "2048"); ISSUE(B1[2], w8sB, "2048");
    ISSUE(B0[3], w8sA, "3072"); ISSUE(B1[3], w8sB, "3072");

#define STEP(CC, PA, PB, OFFLIT)                                             \
    {                                                                        \
        const int s_ = (CC) & 3;                                             \
        asm volatile("s_waitcnt vmcnt(6)"                                    \
                     : "+v"(B0[s_]), "+v"(B1[s_]));                          \
        __builtin_amdgcn_sched_barrier(0x3F7); /* MFMA may not hoist */      \
        const int4v bv0 = B0[s_];                                            \
        const int4v bv1 = B1[s_];                                            \
        const int g0 = ((((CC) << 1) | half) ^ f0) << 2;                     \
        const int g1 = ((((CC) << 1) | half) ^ f1) << 2;                     \
        const int4v av0 = *(const int4v*)&xt[cb0 + g0];                      \
        const int4v av1 = *(const int4v*)&xt[cb1 + g1];                      \
        a00 = __builtin_amdgcn_mfma_i32_32x32x32_i8(av0, bv0, a00, 0, 0, 0); \
        a01 = __builtin_amdgcn_mfma_i32_32x32x32_i8(av0, bv1, a01, 0, 0, 0); \
        a10 = __builtin_amdgcn_mfma_i32_32x32x32_i8(av1, bv0, a10, 0, 0, 0); \
        a11 = __builtin_amdgcn_mfma_i32_32x32x32_i8(av1, bv1, a11, 0, 0, 0); \
        ISSUE(B0[s_], PA, OFFLIT);                                           \
        ISSUE(B1[s_], PB, OFFLIT);                                           \
    }

#pragma unroll 1
    for (int t = 0; t < 9; ++t) {
        const int kh = (t * 11) >> 5;                  // t/3 for t<9
        const int kw = t - kh * 3;
        const int cb0 = ((rb0 + kh) * 58 + w_0 + kw) * 64;
        const int f0  = (w_0 + kw + 2 * (rb0 + kh)) & 15;
        const int cb1 = ((rb1 + kh) * 58 + w_1 + kw) * 64;
        const int f1  = (w_1 + kw + 2 * (rb1 + kh)) & 15;

        // prefetch bases: steps t*8+c+4. c<4 -> this tap (+4096); c>=4 ->
        // next tap (clamped at t=8: redundant reloads, drained below).
        const uint8_t* pT4A = w8sA + (size_t)t * 8192 + 4096;
        const uint8_t* pT4B = pT4A + CGBYTES;
        const int tn = (t < 8) ? (t + 1) : 8;
        const uint8_t* pNA = w8sA + (size_t)tn * 8192;
        const uint8_t* pNB = pNA + CGBYTES;

        STEP(0, pT4A, pT4B, "0")
        STEP(1, pT4A, pT4B, "1024")
        STEP(2, pT4A, pT4B, "2048")
        STEP(3, pT4A, pT4B, "3072")
        STEP(4, pNA,  pNB,  "0")
        STEP(5, pNA,  pNB,  "1024")
        STEP(6, pNA,  pNB,  "2048")
        STEP(7, pNA,  pNB,  "3072")
    }
#undef STEP
#undef ISSUE

    // ---- drain: the last 8 prefetch loads are still in flight and target
    // B0/B1's registers. Wait for them WITH the slots tied live, so the
    // register allocator cannot recycle those VGPRs into the epilogue
    // before the async writebacks land (R12's NaN bug).
    asm volatile("s_waitcnt vmcnt(0)"
        : "+v"(B0[0]), "+v"(B0[1]), "+v"(B0[2]), "+v"(B0[3]),
          "+v"(B1[0]), "+v"(B1[1]), "+v"(B1[2]), "+v"(B1[3]));

    // ---- epilogue: 4 rounds of 32 px through LDS transpose (obuf <= xt).
    // Round r: mg (r>>1), frag (r&1); round 3 rows >=16 are clamp-garbage.
    __syncthreads();                      // all xt reads done
    float* obuf = (float*)xt;             // [32][257] floats = 32896 B
    float* ob = out + (size_t)b * (COUT * HW);

#pragma unroll 1
    for (int r = 0; r < 4; ++r) {
        if (mg == (r >> 1)) {
            const int rfr = r & 1;
#pragma unroll
            for (int reg = 0; reg < 16; ++reg) {
                const int row = (reg & 3) + ((reg >> 2) << 3) + (half << 2);
                if (r == 3 && row >= 16) continue;    // invalid px 112..127
                if (rfr == 0) {
                    obuf[row * 257 + co0] = s0 * (float)a00[reg];
                    obuf[row * 257 + co1] = s1 * (float)a01[reg];
                } else {
                    obuf[row * 257 + co0] = s0 * (float)a10[reg];
                    obuf[row * 257 + co1] = s1 * (float)a11[reg];
                }
            }
        }
        __syncthreads();
        const int k  = tid & 31;          // px within round
        const int cb = tid >> 5;          // 0..15
        const int pxb = p0 + r * 32;
        if (r < 3 || k < 16) {
#pragma unroll
            for (int j = 0; j < 16; ++j) {
                const int co = cb + 16 * j;
                ob[(size_t)co * HW + pxb + k] = obuf[k * 257 + co];
            }
        }
        __syncthreads();
    }
}

// ---------------------------------------------------------------------------
// C (fallback, ws too small for W8): exact R7 kernel — verified pass @140us.
// ---------------------------------------------------------------------------
__global__ __launch_bounds__(512, 2) void conv_mfma_kernel(
    const uint32_t* __restrict__ xbits, const unsigned short* __restrict__ wbT,
    const float* __restrict__ sa_g, float* __restrict__ out)
{
    __shared__ __align__(16) int xt[348 * 64];

    const int tid  = threadIdx.x;
    const int lane = tid & 63;
    const int half = lane >> 5;
    const int l31  = lane & 31;
    const int wid  = tid >> 6;
    const int mg   = wid >> 2;
    const int ng   = wid & 3;

    const int blk = blockIdx.x;
    const int b   = blk / 25;
    const int T   = blk - b * 25;
    const int p0  = T * 128;
    const bool full = (T < 24);
    const int mgE = full ? mg : 0;
    const int h0  = p0 / 56;

    {
        const uint32_t* xb = xbits + (size_t)b * (HW * WORDS);
        for (int u = tid; u < 348 * 32; u += 512) {
            const int cell = u >> 5, p = u & 31;
            const int row = cell / 58;
            const int col = cell - row * 58;
            const int hh = h0 - 1 + row, ww = col - 1;
            const bool ok = (hh >= 0) && (hh < Hdim) && (ww >= 0) && (ww < Wdim);
            uint32_t byteval = 0;
            if (ok)
                byteval = (xb[((hh * 56 + ww) << 3) + (p >> 2)] >> ((p & 3) * 8)) & 0xFFu;
            uint32_t d0 = nib2pm1(byteval & 15u);
            uint32_t d1 = nib2pm1(byteval >> 4);
            if (!ok) { d0 = 0u; d1 = 0u; }
            const int f   = (col + 2 * row) & 15;
            const int idx = cell * 64 + (((p >> 1) ^ f) << 2) + ((p & 1) << 1);
            *reinterpret_cast<uint2*>(&xt[idx]) = make_uint2(d0, d1);
        }
    }
    __syncthreads();

    const int px0 = p0 + mgE * 64 + l31;
    const int px1 = px0 + 32;
    const int h_0 = px0 / 56, w_0 = px0 - h_0 * 56;
    const int h_1 = px1 / 56, w_1 = px1 - h_1 * 56;
    const int rb0 = h_0 - h0, rb1 = h_1 - h0;

    const int co0 = ng * 64 + l31;
    const int co1 = co0 + 32;
    const float s0 = sa_g[co0], s1 = sa_g[co1];

    const unsigned short* wp0 = wbT + (((half << 8) + co0) << 3);
    const unsigned short* wp1 = wbT + (((half << 8) + co1) << 3);

    int16v a00 = {0,0,0,0,0,0,0,0,0,0,0,0,0,0,0,0};
    int16v a01 = {0,0,0,0,0,0,0,0,0,0,0,0,0,0,0,0};
    int16v a10 = {0,0,0,0,0,0,0,0,0,0,0,0,0,0,0,0};
    int16v a11 = {0,0,0,0,0,0,0,0,0,0,0,0,0,0,0,0};

    uint4 wb0 = *(const uint4*)wp0;
    uint4 wb1 = *(const uint4*)wp1;

#pragma unroll 1
    for (int t = 0; t < 9; ++t) {
        const int tn = (t < 8) ? (t + 1) : 8;
        const uint4 wb0n = *(const uint4*)(wp0 + tn * 4096);
        const uint4 wb1n = *(const uint4*)(wp1 + tn * 4096);

        const int kh = (t * 11) >> 5;
        const int kw = t - kh * 3;
        const int cb0 = ((rb0 + kh) * 58 + w_0 + kw) * 64;
        const int f0  = (w_0 + kw + 2 * (rb0 + kh)) & 15;
        const int cb1 = ((rb1 + kh) * 58 + w_1 + kw) * 64;
        const int f1  = (w_1 + kw + 2 * (rb1 + kh)) & 15;

#pragma unroll
        for (int c = 0; c < 8; ++c) {
            const int g0 = ((((c << 1) | half) ^ f0) << 2);
            const int g1 = ((((c << 1) | half) ^ f1) << 2);
            const int4v av0 = *(const int4v*)&xt[cb0 + g0];
            const int4v av1 = *(const int4v*)&xt[cb1 + g1];
            const int4v bv0 = expand_pm1(ext16(wb0, c));
            const int4v bv1 = expand_pm1(ext16(wb1, c));
            a00 = __builtin_amdgcn_mfma_i32_32x32x32_i8(av0, bv0, a00, 0, 0, 0);
            a01 = __builtin_amdgcn_mfma_i32_32x32x32_i8(av0, bv1, a01, 0, 0, 0);
            a10 = __builtin_amdgcn_mfma_i32_32x32x32_i8(av1, bv0, a10, 0, 0, 0);
            a11 = __builtin_amdgcn_mfma_i32_32x32x32_i8(av1, bv1, a11, 0, 0, 0);
        }
        wb0 = wb0n; wb1 = wb1n;
    }

    if (full || mg == 0) {
        float* ob = out + (size_t)b * (COUT * HW);
        const int pxb = p0 + mgE * 64;
#pragma unroll
        for (int reg = 0; reg < 16; ++reg) {
            const int row = (reg & 3) + ((reg >> 2) << 3) + (half << 2);
            ob[(size_t)co0 * HW + pxb + row]      = s0 * (float)a00[reg];
            ob[(size_t)co1 * HW + pxb + row]      = s1 * (float)a01[reg];
            ob[(size_t)co0 * HW + pxb + 32 + row] = s0 * (float)a10[reg];
            ob[(size_t)co1 * HW + pxb + 32 + row] = s1 * (float)a11[reg];
        }
    }
}

extern "C" void kernel_launch(void* const* d_in, const int* in_sizes, int n_in,
                              void* d_out, int out_size, void* d_ws, size_t ws_size,
                              hipStream_t stream) {
    const float* x     = (const float*)d_in[0];   // [32,256,56,56]
    const float* wts   = (const float*)d_in[1];   // [4,256,256,3,3]
    const float* RV    = (const float*)d_in[2];   // [5]
    const float* alpha = (const float*)d_in[3];   // [256,1,1]
    float* out = (float*)d_out;                   // [32,256,56,56]

    uint8_t* ws = (uint8_t*)d_ws;
    unsigned short* wbT = (unsigned short*)(ws + OFF_WBT);
    float*    sa    = (float*)   (ws + OFF_SA);
    uint32_t* xbits = (uint32_t*)(ws + OFF_XBITS);
    uint4*    w8    = (uint4*)   (ws + OFF_W8);

    const int has_w8 = (ws_size >= (size_t)WS_NEED) ? 1 : 0;

    prep_w_kernel<<<COUT, 256, 0, stream>>>(wts, RV, alpha, wbT, sa, w8, has_w8);
    pack_x_kernel<<<NPIX / 256, 256, 0, stream>>>(x, xbits);
    if (has_w8)
        conv_mfma_w8_kernel<<<BATCH * 28, 512, 0, stream>>>(
            xbits, (const uint8_t*)w8, sa, out);
    else
        conv_mfma_kernel<<<BATCH * 25, 512, 0, stream>>>(xbits, wbT, sa, out);
}